// Round 2
// baseline (3954.225 us; speedup 1.0000x reference)
//
#include <hip/hip_runtime.h>
#include <hip/hip_bf16.h>
#include <math.h>

// Problem: B=64, T=1000, S=96, A=32, INP=128, H=256.  All I/O is float32.
// pre[br][b*1000+t][j] staged fp32 in d_ws: 2 * 64000 * 256 floats = 131.072 MB

// ---------------------------------------------------------------------------
// Kernel 1: fused feed-forward. Per block: 64 rows of X.
//   X1 = relu(X @ Wa + ba)   [64 x 256]
//   pre = X1 @ Wi + (b_hh + b_ih)
// Thread t owns output column c=t; weight column held in VGPRs; X tiles in LDS
// read as wave-uniform broadcasts (conflict-free).
// ---------------------------------------------------------------------------
__global__ __launch_bounds__(256, 1)
void ff_kernel(const float* __restrict__ state,
               const float* __restrict__ action,
               const float* __restrict__ fc11_w, const float* __restrict__ fc11_b,
               const float* __restrict__ W_ih1,
               const float* __restrict__ b_hh1, const float* __restrict__ b_ih1,
               const float* __restrict__ fc21_w, const float* __restrict__ fc21_b,
               const float* __restrict__ W_ih2,
               const float* __restrict__ b_hh2, const float* __restrict__ b_ih2,
               float* __restrict__ pre_out)
{
    __shared__ float Xs[64 * 128];    // 32 KB
    __shared__ float X1s[64 * 256];   // 64 KB

    const int tile = blockIdx.x % 1000;
    const int br   = blockIdx.x / 1000;
    const float* Wa = br ? fc21_w : fc11_w;
    const float* ba = br ? fc21_b : fc11_b;
    const float* Wi = br ? W_ih2 : W_ih1;
    const float* bh = br ? b_hh2 : b_hh1;
    const float* bi = br ? b_ih2 : b_ih1;
    float* pre = pre_out + (size_t)br * 64000u * 256u;

    const int tid  = threadIdx.x;
    const int row0 = tile * 64;

    // stage X = concat(state, action): rows row0..row0+63 contiguous in memory
    for (int f = tid; f < 64 * 96; f += 256) {
        int r = f / 96, cc = f % 96;
        Xs[r * 128 + cc] = state[(size_t)row0 * 96 + f];
    }
    for (int f = tid; f < 64 * 32; f += 256) {
        int r = f / 32, cc = f % 32;
        Xs[r * 128 + 96 + cc] = action[(size_t)row0 * 32 + f];
    }
    __syncthreads();

    const int c = tid;

    // ---- phase B: X1 = relu(X @ Wa + ba), column c per thread ----
    float wa[128];
#pragma unroll
    for (int k = 0; k < 128; ++k) wa[k] = Wa[k * 256 + c];
    const float bac = ba[c];

    for (int r = 0; r < 64; ++r) {
        const float4* xr = (const float4*)&Xs[r * 128];
        float a0 = bac, a1 = 0.f, a2 = 0.f, a3 = 0.f;
#pragma unroll
        for (int k4 = 0; k4 < 32; ++k4) {
            float4 x4 = xr[k4];
            a0 += x4.x * wa[4 * k4 + 0];
            a1 += x4.y * wa[4 * k4 + 1];
            a2 += x4.z * wa[4 * k4 + 2];
            a3 += x4.w * wa[4 * k4 + 3];
        }
        float v = (a0 + a1) + (a2 + a3);
        X1s[r * 256 + c] = v > 0.f ? v : 0.f;
    }
    __syncthreads();

    // ---- phase C: pre = X1 @ Wi + bias ----
    float wi[256];
#pragma unroll
    for (int k = 0; k < 256; ++k) wi[k] = Wi[k * 256 + c];
    const float bias = bh[c] + bi[c];

    for (int r = 0; r < 64; ++r) {
        const float4* xr = (const float4*)&X1s[r * 256];
        float a0 = bias, a1 = 0.f, a2 = 0.f, a3 = 0.f;
#pragma unroll
        for (int k4 = 0; k4 < 64; ++k4) {
            float4 x4 = xr[k4];
            a0 += x4.x * wi[4 * k4 + 0];
            a1 += x4.y * wi[4 * k4 + 1];
            a2 += x4.z * wi[4 * k4 + 2];
            a3 += x4.w * wi[4 * k4 + 3];
        }
        pre[(size_t)(row0 + r) * 256 + c] = (a0 + a1) + (a2 + a3);
    }
}

// ---------------------------------------------------------------------------
// Kernel 2: recurrence + q head. One block per (branch, batch): 128 blocks.
// Thread j holds W_hh[:, j] in 256 VGPRs. h double-buffered in LDS.
//   h_t = sigmoid(h_{t-1} @ W_hh + pre_t);  q_t = h_t . qw + qb
// ---------------------------------------------------------------------------
__global__ __launch_bounds__(256, 1)
void rnn_kernel(const float* __restrict__ pre_all,
                const float* __restrict__ hn,
                const float* __restrict__ W_hh1,
                const float* __restrict__ fc12_w, const float* __restrict__ fc12_b,
                const float* __restrict__ W_hh2,
                const float* __restrict__ fc22_w, const float* __restrict__ fc22_b,
                float* __restrict__ out)
{
    __shared__ float hbuf[2][256];
    __shared__ float qpart[4];

    const int wg = blockIdx.x;      // 0..127
    const int br = wg >> 6;
    const int b  = wg & 63;
    const float* Whh = br ? W_hh2 : W_hh1;
    const float* qwp = br ? fc22_w : fc12_w;
    const float qb   = br ? fc22_b[0] : fc12_b[0];
    const float* pre = pre_all + ((size_t)br * 64000u + (size_t)b * 1000u) * 256u;
    float* qout = out + (size_t)br * 64000u + (size_t)b * 1000u;

    const int j = threadIdx.x;

    float w[256];
#pragma unroll
    for (int k = 0; k < 256; ++k) w[k] = Whh[k * 256 + j];
    const float qw = qwp[j];

    hbuf[0][j] = hn[b * 256 + j];
    __syncthreads();

    const int lane = j & 63;
    const int wid  = j >> 6;

    // 2-deep prefetch of pre (HBM latency ~900 cyc vs ~600 cyc/step)
    float pre_c = pre[j];
    float pre_n = pre[256 + j];
    int p = 0;

    for (int t = 0; t < 1000; ++t) {
        const int t2 = (t + 2 < 1000) ? (t + 2) : 999;
        const float pre_n2 = pre[(size_t)t2 * 256 + j];

        const float4* hb = (const float4*)&hbuf[p][0];
        float a0 = pre_c, a1 = 0.f, a2 = 0.f, a3 = 0.f;
#pragma unroll
        for (int k4 = 0; k4 < 64; ++k4) {
            float4 h4 = hb[k4];   // wave-uniform broadcast, conflict-free
            a0 += h4.x * w[4 * k4 + 0];
            a1 += h4.y * w[4 * k4 + 1];
            a2 += h4.z * w[4 * k4 + 2];
            a3 += h4.w * w[4 * k4 + 3];
        }
        const float z = (a0 + a1) + (a2 + a3);
        const float h = 1.0f / (1.0f + __expf(-z));

        // fused q head: block-reduce h*qw
        float v = h * qw;
#pragma unroll
        for (int off = 32; off > 0; off >>= 1) v += __shfl_xor(v, off, 64);
        if (lane == 0) qpart[wid] = v;

        hbuf[p ^ 1][j] = h;
        __syncthreads();                      // publishes h_new and qpart
        if (j == 0)
            qout[t] = qpart[0] + qpart[1] + qpart[2] + qpart[3] + qb;
        __syncthreads();                      // protects qpart/h reuse next step

        p ^= 1;
        pre_c = pre_n;
        pre_n = pre_n2;
    }
}

// ---------------------------------------------------------------------------
extern "C" void kernel_launch(void* const* d_in, const int* in_sizes, int n_in,
                              void* d_out, int out_size, void* d_ws, size_t ws_size,
                              hipStream_t stream)
{
    const float* state  = (const float*)d_in[0];
    const float* action = (const float*)d_in[1];
    const float* hn     = (const float*)d_in[2];
    const float* fc11_w = (const float*)d_in[3];
    const float* fc11_b = (const float*)d_in[4];
    const float* W_hh1  = (const float*)d_in[5];
    const float* W_ih1  = (const float*)d_in[6];
    const float* b_hh1  = (const float*)d_in[7];
    const float* b_ih1  = (const float*)d_in[8];
    const float* fc12_w = (const float*)d_in[9];
    const float* fc12_b = (const float*)d_in[10];
    const float* fc21_w = (const float*)d_in[11];
    const float* fc21_b = (const float*)d_in[12];
    const float* W_hh2  = (const float*)d_in[13];
    const float* W_ih2  = (const float*)d_in[14];
    const float* b_hh2  = (const float*)d_in[15];
    const float* b_ih2  = (const float*)d_in[16];
    const float* fc22_w = (const float*)d_in[17];
    const float* fc22_b = (const float*)d_in[18];

    float* pre = (float*)d_ws;   // needs 2*64000*256*4 = 131.072 MB

    ff_kernel<<<2000, 256, 0, stream>>>(state, action,
                                        fc11_w, fc11_b, W_ih1, b_hh1, b_ih1,
                                        fc21_w, fc21_b, W_ih2, b_hh2, b_ih2,
                                        pre);
    rnn_kernel<<<128, 256, 0, stream>>>(pre, hn,
                                        W_hh1, fc12_w, fc12_b,
                                        W_hh2, fc22_w, fc22_b,
                                        (float*)d_out);
}

// Round 3
// 1044.927 us; speedup vs baseline: 3.7842x; 3.7842x over previous
//
#include <hip/hip_runtime.h>
#include <hip/hip_bf16.h>
#include <math.h>

// B=64, T=1000, S=96, A=32, INP=128, H=256. All I/O fp32.
// d_ws layout: pre fp16 [2][64000][256] = 65.536 MB, then h fp16 [2][64000][256] = 65.536 MB.

typedef _Float16 half2_t __attribute__((ext_vector_type(2)));

__device__ __forceinline__ float fdot2(half2_t a, half2_t b, float c) {
#if __has_builtin(__builtin_amdgcn_fdot2)
    return __builtin_amdgcn_fdot2(a, b, c, false);   // v_dot2_f32_f16
#else
    return c + (float)a[0] * (float)b[0] + (float)a[1] * (float)b[1];
#endif
}

// ---------------------------------------------------------------------------
// Kernel 1: feed-forward, fp16 data / fp32 accumulate.
//   X1 = relu(X @ Wa + ba); pre = X1 @ Wi + (b_hh+b_ih)  -> fp16
// Thread c owns output column c; weight column in VGPRs as half2;
// X rows read from LDS as broadcast ds_read_b128 (8 halves each).
// ---------------------------------------------------------------------------
__global__ __launch_bounds__(256, 2)
void ff_kernel(const float* __restrict__ state,
               const float* __restrict__ action,
               const float* __restrict__ fc11_w, const float* __restrict__ fc11_b,
               const float* __restrict__ W_ih1,
               const float* __restrict__ b_hh1, const float* __restrict__ b_ih1,
               const float* __restrict__ fc21_w, const float* __restrict__ fc21_b,
               const float* __restrict__ W_ih2,
               const float* __restrict__ b_hh2, const float* __restrict__ b_ih2,
               _Float16* __restrict__ pre_out)
{
    __shared__ half2_t Xsh[64 * 64];     // 16 KB: 64 rows x 64 half2 (128 cols)
    __shared__ _Float16 X1h[64 * 256];   // 32 KB

    const int tile = blockIdx.x % 1000;
    const int br   = blockIdx.x / 1000;
    const float* Wa = br ? fc21_w : fc11_w;
    const float* ba = br ? fc21_b : fc11_b;
    const float* Wi = br ? W_ih2 : W_ih1;
    const float* bh = br ? b_hh2 : b_hh1;
    const float* bi = br ? b_ih2 : b_ih1;

    const int tid  = threadIdx.x;
    const int row0 = tile * 64;

    // stage X = concat(state, action) as half2 pairs (cols 2i, 2i+1)
    const float2* st2 = (const float2*)(state + (size_t)row0 * 96);
    for (int p = tid; p < 64 * 48; p += 256) {
        int r = p / 48, i = p % 48;
        float2 v = st2[r * 48 + i];
        Xsh[r * 64 + i] = half2_t{(_Float16)v.x, (_Float16)v.y};
    }
    const float2* ac2 = (const float2*)(action + (size_t)row0 * 32);
    for (int p = tid; p < 64 * 16; p += 256) {
        int r = p / 16, i = p % 16;
        float2 v = ac2[r * 16 + i];
        Xsh[r * 64 + 48 + i] = half2_t{(_Float16)v.x, (_Float16)v.y};
    }
    __syncthreads();

    const int c = tid;

    // ---- phase B: X1 = relu(X @ Wa + ba) ----
    {
        half2_t wa[64];
#pragma unroll
        for (int i = 0; i < 64; ++i)
            wa[i] = half2_t{(_Float16)Wa[(2 * i) * 256 + c],
                            (_Float16)Wa[(2 * i + 1) * 256 + c]};
        const float bac = ba[c];

        for (int r = 0; r < 64; ++r) {
            const float4* xr = (const float4*)&Xsh[r * 64];
            float s0 = bac, s1 = 0.f, s2 = 0.f, s3 = 0.f;
#pragma unroll
            for (int k = 0; k < 16; ++k) {
                float4 v = xr[k];                     // 8 halves, broadcast
                const half2_t* hh = (const half2_t*)&v;
                s0 = fdot2(hh[0], wa[4 * k + 0], s0);
                s1 = fdot2(hh[1], wa[4 * k + 1], s1);
                s2 = fdot2(hh[2], wa[4 * k + 2], s2);
                s3 = fdot2(hh[3], wa[4 * k + 3], s3);
            }
            float v = (s0 + s1) + (s2 + s3);
            X1h[r * 256 + c] = (_Float16)(v > 0.f ? v : 0.f);
        }
    }
    __syncthreads();

    // ---- phase C: pre = X1 @ Wi + bias ----
    {
        half2_t wi[128];
#pragma unroll
        for (int i = 0; i < 128; ++i)
            wi[i] = half2_t{(_Float16)Wi[(2 * i) * 256 + c],
                            (_Float16)Wi[(2 * i + 1) * 256 + c]};
        const float bias = bh[c] + bi[c];
        _Float16* pre = pre_out + (size_t)br * 64000u * 256u;

        for (int r = 0; r < 64; ++r) {
            const float4* xr = (const float4*)&X1h[r * 256];
            float s0 = bias, s1 = 0.f, s2 = 0.f, s3 = 0.f;
#pragma unroll
            for (int k = 0; k < 32; ++k) {
                float4 v = xr[k];
                const half2_t* hh = (const half2_t*)&v;
                s0 = fdot2(hh[0], wi[4 * k + 0], s0);
                s1 = fdot2(hh[1], wi[4 * k + 1], s1);
                s2 = fdot2(hh[2], wi[4 * k + 2], s2);
                s3 = fdot2(hh[3], wi[4 * k + 3], s3);
            }
            pre[(size_t)(row0 + r) * 256 + c] = (_Float16)((s0 + s1) + (s2 + s3));
        }
    }
}

// ---------------------------------------------------------------------------
// Kernel 2: recurrence only. One block per (branch,batch) = 128 blocks.
// h fp16 in LDS (512 B/step -> 32 ds_read_b128/thread), w as 128 half2 VGPRs,
// 128 fdot2/thread/step, ONE barrier/step. h written fp16 to global for the
// q-head kernel (removes shuffle-reduce + 2nd barrier from critical path).
// ---------------------------------------------------------------------------
__global__ __launch_bounds__(256, 1)
void rnn_kernel(const _Float16* __restrict__ pre_all,
                const float* __restrict__ hn,
                const float* __restrict__ W_hh1,
                const float* __restrict__ W_hh2,
                _Float16* __restrict__ h_out)
{
    __shared__ _Float16 hbuf[2][256];

    const int wg = blockIdx.x;      // 0..127
    const int br = wg >> 6;
    const int b  = wg & 63;
    const float* Whh = br ? W_hh2 : W_hh1;
    const _Float16* pre = pre_all + ((size_t)br * 64000u + (size_t)b * 1000u) * 256u;
    _Float16* hg = h_out + ((size_t)br * 64000u + (size_t)b * 1000u) * 256u;

    const int j = threadIdx.x;

    half2_t wh[128];
#pragma unroll
    for (int i = 0; i < 128; ++i)
        wh[i] = half2_t{(_Float16)Whh[(2 * i) * 256 + j],
                        (_Float16)Whh[(2 * i + 1) * 256 + j]};

    hbuf[0][j] = (_Float16)hn[b * 256 + j];
    __syncthreads();

    // 2-deep prefetch of pre
    float pre_c = (float)pre[j];
    float pre_n = (float)pre[256 + j];
    int p = 0;

    for (int t = 0; t < 1000; ++t) {
        const int t2 = (t + 2 < 1000) ? (t + 2) : 999;
        const float pre_n2 = (float)pre[(size_t)t2 * 256 + j];

        const float4* hb = (const float4*)&hbuf[p][0];
        float s0 = pre_c, s1 = 0.f, s2 = 0.f, s3 = 0.f;
#pragma unroll
        for (int k = 0; k < 32; ++k) {
            float4 v = hb[k];                       // 8 halves, broadcast
            const half2_t* hh = (const half2_t*)&v;
            s0 = fdot2(hh[0], wh[4 * k + 0], s0);
            s1 = fdot2(hh[1], wh[4 * k + 1], s1);
            s2 = fdot2(hh[2], wh[4 * k + 2], s2);
            s3 = fdot2(hh[3], wh[4 * k + 3], s3);
        }
        const float z = (s0 + s1) + (s2 + s3);
        const float h = 1.0f / (1.0f + __expf(-z));

        const _Float16 h16 = (_Float16)h;
        hbuf[p ^ 1][j] = h16;
        hg[(size_t)t * 256 + j] = h16;              // fire-and-forget store
        __syncthreads();                            // publishes h for step t+1

        p ^= 1;
        pre_c = pre_n;
        pre_n = pre_n2;
    }
}

// ---------------------------------------------------------------------------
// Kernel 3: q head. q[n] = h[n,:] . qw + qb, n = br*64000 + b*1000 + t.
// One thread per output; 32 global b128 loads + 128 fdot2 each. ~65 MB read.
// ---------------------------------------------------------------------------
__global__ __launch_bounds__(256, 2)
void q_kernel(const _Float16* __restrict__ h_all,
              const float* __restrict__ fc12_w, const float* __restrict__ fc12_b,
              const float* __restrict__ fc22_w, const float* __restrict__ fc22_b,
              float* __restrict__ out)
{
    const int n  = blockIdx.x * 256 + threadIdx.x;    // grid = 500 blocks -> n < 128000
    const int br = (n >= 64000);                      // uniform per block (250*256 = 64000)
    const float* qwp = br ? fc22_w : fc12_w;
    const float  qb  = br ? fc22_b[0] : fc12_b[0];

    half2_t qw[128];
#pragma unroll
    for (int i = 0; i < 128; ++i)
        qw[i] = half2_t{(_Float16)qwp[2 * i], (_Float16)qwp[2 * i + 1]};

    const float4* hr = (const float4*)(h_all + (size_t)n * 256u);
    float s0 = qb, s1 = 0.f, s2 = 0.f, s3 = 0.f;
#pragma unroll
    for (int k = 0; k < 32; ++k) {
        float4 v = hr[k];
        const half2_t* hh = (const half2_t*)&v;
        s0 = fdot2(hh[0], qw[4 * k + 0], s0);
        s1 = fdot2(hh[1], qw[4 * k + 1], s1);
        s2 = fdot2(hh[2], qw[4 * k + 2], s2);
        s3 = fdot2(hh[3], qw[4 * k + 3], s3);
    }
    out[n] = (s0 + s1) + (s2 + s3);
}

// ---------------------------------------------------------------------------
extern "C" void kernel_launch(void* const* d_in, const int* in_sizes, int n_in,
                              void* d_out, int out_size, void* d_ws, size_t ws_size,
                              hipStream_t stream)
{
    const float* state  = (const float*)d_in[0];
    const float* action = (const float*)d_in[1];
    const float* hn     = (const float*)d_in[2];
    const float* fc11_w = (const float*)d_in[3];
    const float* fc11_b = (const float*)d_in[4];
    const float* W_hh1  = (const float*)d_in[5];
    const float* W_ih1  = (const float*)d_in[6];
    const float* b_hh1  = (const float*)d_in[7];
    const float* b_ih1  = (const float*)d_in[8];
    const float* fc12_w = (const float*)d_in[9];
    const float* fc12_b = (const float*)d_in[10];
    const float* fc21_w = (const float*)d_in[11];
    const float* fc21_b = (const float*)d_in[12];
    const float* W_hh2  = (const float*)d_in[13];
    const float* W_ih2  = (const float*)d_in[14];
    const float* b_hh2  = (const float*)d_in[15];
    const float* b_ih2  = (const float*)d_in[16];
    const float* fc22_w = (const float*)d_in[17];
    const float* fc22_b = (const float*)d_in[18];

    _Float16* pre = (_Float16*)d_ws;                    // 2*64000*256 halves = 65.536 MB
    _Float16* hbg = (_Float16*)d_ws + 32768000u;        // + 65.536 MB = 131.072 MB total

    ff_kernel<<<2000, 256, 0, stream>>>(state, action,
                                        fc11_w, fc11_b, W_ih1, b_hh1, b_ih1,
                                        fc21_w, fc21_b, W_ih2, b_hh2, b_ih2,
                                        pre);
    rnn_kernel<<<128, 256, 0, stream>>>(pre, hn, W_hh1, W_hh2, hbg);
    q_kernel<<<500, 256, 0, stream>>>(hbg, fc12_w, fc12_b, fc22_w, fc22_b,
                                      (float*)d_out);
}